// Round 2
// baseline (488.576 us; speedup 1.0000x reference)
//
#include <hip/hip_runtime.h>
#include <hip/hip_bf16.h>

typedef unsigned short u16;
typedef unsigned long long u64;
typedef short bf16x8 __attribute__((ext_vector_type(8)));
typedef float f32x4 __attribute__((ext_vector_type(4)));

#define EQ_SCALE   0.04419417382415922f     /* 1/sqrt(512) */
#define CONV_SCALE 0.014731391274719738f    /* 1/sqrt(512*9) */

// workspace layout (bytes)
#define WS_S   0                                  // f32 [8][512]
#define WS_ESC (16*1024)                          // f32 [8][512]  = conv_scale*demod
#define WS_WSQ (32*1024)                          // f32 [512][512]
#define WS_WT  (32*1024 + 1024*1024)              // bf16 [9][8][32][2][64][8] frag-native
#define WS_XS  (WS_WT + 9*512*512*2)              // bf16 [8][64][64][512] (b, y, x, ci)
#define WS_Z   (WS_XS + 8*64*64*512*2)            // bf16 zero page, 64 KB

__device__ __forceinline__ void gld16(void* l, const void* g) {
  __builtin_amdgcn_global_load_lds((const __attribute__((address_space(1))) void*)g,
                                   (__attribute__((address_space(3))) void*)l,
                                   16, 0, 0);
}

// round-to-nearest-even f32 -> bf16 bits
__device__ __forceinline__ u16 f2b_rne(float f) {
  union { float f; unsigned int i; } c; c.f = f;
  unsigned int r = (c.i + 0x7FFFu + ((c.i >> 16) & 1u)) >> 16;
  return (u16)r;
}

// s[b][i] = eq_scale * sum_j style[b][j]*modw[i][j] + mod_bias[i]
__global__ void k_style(const float* __restrict__ style, const float* __restrict__ mw,
                        const float* __restrict__ mb, float* __restrict__ s) {
  int idx = blockIdx.x * 256 + threadIdx.x;      // 4096
  int b = idx >> 9, i = idx & 511;
  const float* sr = style + (b << 9);
  const float* wr = mw + (i << 9);
  float acc = 0.f;
  for (int j = 0; j < 512; ++j) acc += sr[j] * wr[j];
  s[idx] = acc * EQ_SCALE + mb[i];
}

// wsq[o][i] = sum_khw weight[o][i][khw]^2
__global__ void k_wsq(const float* __restrict__ w, float* __restrict__ wsq) {
  int idx = blockIdx.x * 256 + threadIdx.x;      // 262144
  const float* p = w + idx * 9;
  float a = 0.f;
  for (int t = 0; t < 9; ++t) { float v = p[t]; a += v * v; }
  wsq[idx] = a;
}

// esc[b][o] = conv_scale * rsqrt(conv_scale^2 * sum_i wsq[o][i]*s[b][i]^2 + 1e-8)
__global__ void k_esc(const float* __restrict__ wsq, const float* __restrict__ s,
                      float* __restrict__ esc) {
  int idx = blockIdx.x * 256 + threadIdx.x;      // 4096
  int b = idx >> 9, o = idx & 511;
  const float* wr = wsq + (o << 9);
  const float* sr = s + (b << 9);
  float a = 0.f;
  for (int i = 0; i < 512; ++i) { float sv = sr[i]; a += wr[i] * sv * sv; }
  esc[idx] = CONV_SCALE * rsqrtf(CONV_SCALE * CONV_SCALE * a + 1e-8f);
}

// zero page for OOB-row staging redirect
__global__ void k_zero(u64* __restrict__ z) {
  z[blockIdx.x * 256 + threadIdx.x] = 0ull;      // 32*256*8 = 64 KB
}

// wt2: fragment-native layout. elem addr =
//   khw*262144 + cib*32768 + og*1024 + ks*512 + lane*8 + j
// where lane l holds A[o = og*16 + (l&15)][ci = cib*64 + ks*32 + ((l>>4)&3)*8 + j]
__global__ void k_wt(const float* __restrict__ w, u16* __restrict__ wt2) {
  int idx = blockIdx.x * 256 + threadIdx.x;      // 262144 = o*512 + ci
  int o = idx >> 9, ci = idx & 511;
  const float* p = w + idx * 9;
  int og = o >> 4;
  int lane = (o & 15) | (((ci >> 3) & 3) << 4);
  int cib = ci >> 6, ks = (ci >> 5) & 1, j = ci & 7;
  int base = cib * 32768 + og * 1024 + ks * 512 + lane * 8 + j;
  for (int khw = 0; khw < 9; ++khw)
    wt2[khw * 262144 + base] = f2b_rne(p[khw]);
}

// xs[b][y][x][i] = bf16( x[b][i][y][x] * s[b][i] )   (NCHW->NHWC transpose + scale)
__global__ void k_xs(const float* __restrict__ x, const float* __restrict__ s,
                     u16* __restrict__ xs) {
  __shared__ u16 tile[64 * 66];
  int by = blockIdx.x;                 // b*64 + y
  int i0 = blockIdx.y << 6;
  int b = by >> 6, y = by & 63;
  int t = threadIdx.x, w = t >> 6, lane = t & 63;
  for (int k = 0; k < 16; ++k) {
    int il = w + (k << 2);
    int i = i0 + il;
    float v = x[((((b << 9) + i) << 6) | y) << 6 | lane] * s[(b << 9) + i];
    tile[lane * 66 + il] = f2b_rne(v);
  }
  __syncthreads();
  for (int k = 0; k < 16; ++k) {
    int xc = w + (k << 2);
    xs[((((b << 6) | y) << 6 | xc) << 9) + i0 + lane] = tile[xc * 66 + lane];
  }
}

// Conv: implicit GEMM, A (weights) global->register (frag-native wt2, L2-resident),
// B (xs) in LDS double-buffered. Block 256(o) x 256(pos: 4 rows x 64 cols),
// 8 waves = 4(o) x 2(row-pair), wave tile 64(o) x 128(pos). ONE barrier per ci-block.
__global__ void __launch_bounds__(512, 2) k_conv(
    const u16* __restrict__ wt2, const u16* __restrict__ xs,
    const u16* __restrict__ zbuf,
    const float* __restrict__ esc, const float* __restrict__ noise,
    const float* __restrict__ nwp, const float* __restrict__ abias,
    float* __restrict__ out) {
  __shared__ __align__(16) u16 ldsB[2][384 * 64];   // 2 x 48 KB: [6 rows x 64 cols][ci]

  const int t = threadIdx.x;
  const int w = t >> 6, lane = t & 63;
  const int wm = w >> 1, wn = w & 1;            // 4(o) x 2(row-pair) wave grid
  const int quad = lane >> 4, l15 = lane & 15;
  const int wn2 = wn << 1;

  // XCD swizzle: flat = by*2+bx; xcd = flat&7; XCDs 0-3 take o-half 0, 4-7 half 1,
  // so each XCD's L2 holds one 2.25 MB wt2 half. Bijective (256 = 32*8).
  const int flat = blockIdx.y * 2 + blockIdx.x;
  const int xcd = flat & 7, sgrp = flat >> 3;
  const int o0 = (xcd >> 2) << 8;               // 0 or 256
  const int nt = sgrp * 4 + (xcd & 3);          // 0..127
  const int b = nt >> 4, y0 = (nt & 15) << 2;

  // B staging source pointers (6 chunks/thread; chunk j covers LDS row tr==j).
  // OOB input rows redirect to the zero page -> no row masking in compute.
  const u16* bgp[6];
#pragma unroll
  for (int j = 0; j < 6; ++j) {
    int c = j * 512 + t;
    int pos = c >> 3, swz = c & 7;
    int ci16 = swz ^ (pos & 7);
    int col = pos & 63;
    int yy = y0 - 1 + j;
    if ((unsigned)yy < 64u)
      bgp[j] = xs + ((((b << 6) + yy) << 6) + col) * 512 + ci16 * 8;
    else
      bgp[j] = zbuf + col * 512 + ci16 * 8;
  }

  const int aoff = o0 * 64 + wm * 4096 + lane * 8;

  f32x4 acc[32];
#pragma unroll
  for (int i = 0; i < 32; ++i) acc[i] = (f32x4)0.f;

  // prologue: stage B[cib=0] -> ldsB[0]
#pragma unroll
  for (int j = 0; j < 6; ++j)
    gld16(&ldsB[0][(j * 512 + w * 64) * 8], bgp[j]);

#pragma unroll 1
  for (int cib = 0; cib < 8; ++cib) {
    __syncthreads();          // B[cib] staged (vmcnt drained) & prev buffer reads done
    const u16* bR = &ldsB[cib & 1][0];
#pragma unroll
    for (int khw = 0; khw < 9; ++khw) {
      const int kh = khw / 3, kw = khw % 3;
      const u16* wp = wt2 + (khw * 8 + cib) * 32768 + aoff;

      // A frags for this tap: 8 x 1KB coalesced global->reg, issued first so
      // their vmcnt wait doesn't include the B prefetch.
      bf16x8 af[2][4];
#pragma unroll
      for (int ks = 0; ks < 2; ++ks)
#pragma unroll
        for (int mf = 0; mf < 4; ++mf)
          af[ks][mf] = *(const bf16x8*)(wp + mf * 1024 + ks * 512);

      // prefetch next ci-block's B tile 2 taps before the barrier
      if (khw == 7 && cib < 7) {
        u16* bW = &ldsB[(cib & 1) ^ 1][0];
#pragma unroll
        for (int j = 0; j < 6; ++j)
          gld16(bW + (j * 512 + w * 64) * 8, bgp[j] + (cib + 1) * 64);
      }

      int bBase[8], bXor[8];
      unsigned cmask[8];
#pragma unroll
      for (int nf = 0; nf < 8; ++nf) {
        const int r = nf >> 2, cg = nf & 3;
        const int tr = wn2 + r + kh;           // 0..5, always in-range
        int ci = cg * 16 + l15 + kw - 1;
        cmask[nf] = ((kw == 0 && cg == 0) || (kw == 2 && cg == 3))
                        ? (unsigned)((unsigned)ci > 63u) : 0u;
        ci &= 63;
        int pos = tr * 64 + ci;
        bBase[nf] = pos * 8;
        bXor[nf] = pos & 7;
      }
#pragma unroll
      for (int ks = 0; ks < 2; ++ks) {
        const int kci = ks * 4 + quad;
        bf16x8 bv[8];
#pragma unroll
        for (int nf = 0; nf < 8; ++nf) {
          bf16x8 v = *(const bf16x8*)(bR + (bBase[nf] + (kci ^ bXor[nf])) * 8);
          bf16x8 z = {0, 0, 0, 0, 0, 0, 0, 0};
          bv[nf] = cmask[nf] ? z : v;
        }
        __builtin_amdgcn_s_setprio(1);
#pragma unroll
        for (int mf = 0; mf < 4; ++mf)
#pragma unroll
          for (int nf = 0; nf < 8; ++nf)
            acc[mf * 8 + nf] = __builtin_amdgcn_mfma_f32_16x16x32_bf16(
                af[ks][mf], bv[nf], acc[mf * 8 + nf], 0, 0, 0);
        __builtin_amdgcn_s_setprio(0);
      }
    }
  }

  // epilogue: scale + noise + bias + leaky_relu*sqrt(2), f32 store
  const float nwv = nwp[0];
#pragma unroll
  for (int mf = 0; mf < 4; ++mf) {
#pragma unroll
    for (int r = 0; r < 4; ++r) {
      int o = o0 + wm * 64 + mf * 16 + quad * 4 + r;
      float es = esc[(b << 9) + o];
      float ab = abias[o];
#pragma unroll
      for (int nf = 0; nf < 8; ++nf) {
        int y = y0 + wn2 + (nf >> 2);
        int col = (nf & 3) * 16 + l15;
        int idx = ((((((b << 9) + o) << 6) | y)) << 6) | col;
        float v = acc[mf * 8 + nf][r] * es + nwv * noise[idx] + ab;
        v = (v < 0.f ? 0.2f * v : v) * 1.4142135623730951f;
        out[idx] = v;
      }
    }
  }
}

extern "C" void kernel_launch(void* const* d_in, const int* in_sizes, int n_in,
                              void* d_out, int out_size, void* d_ws, size_t ws_size,
                              hipStream_t stream) {
  const float* x      = (const float*)d_in[0];
  const float* style  = (const float*)d_in[1];
  const float* noise  = (const float*)d_in[2];
  const float* weight = (const float*)d_in[3];
  const float* mw     = (const float*)d_in[4];
  const float* mb     = (const float*)d_in[5];
  const float* nw     = (const float*)d_in[6];
  const float* ab     = (const float*)d_in[7];
  float* out = (float*)d_out;

  char* ws = (char*)d_ws;
  float* s   = (float*)(ws + WS_S);
  float* esc = (float*)(ws + WS_ESC);
  float* wsq = (float*)(ws + WS_WSQ);
  u16* wt2   = (u16*)(ws + WS_WT);
  u16* xs    = (u16*)(ws + WS_XS);
  u16* zbuf  = (u16*)(ws + WS_Z);

  k_zero<<<32, 256, 0, stream>>>((u64*)zbuf);
  k_style<<<16, 256, 0, stream>>>(style, mw, mb, s);
  k_wsq<<<1024, 256, 0, stream>>>(weight, wsq);
  k_esc<<<16, 256, 0, stream>>>(wsq, s, esc);
  k_wt<<<1024, 256, 0, stream>>>(weight, wt2);
  k_xs<<<dim3(512, 8), 256, 0, stream>>>(x, s, xs);
  k_conv<<<dim3(2, 128), 512, 0, stream>>>(wt2, xs, zbuf, esc, noise, nw, ab, out);
}

// Round 3
// 364.996 us; speedup vs baseline: 1.3386x; 1.3386x over previous
//
#include <hip/hip_runtime.h>
#include <hip/hip_bf16.h>

typedef unsigned short u16;
typedef unsigned long long u64;
typedef short bf16x8 __attribute__((ext_vector_type(8)));
typedef float f32x4 __attribute__((ext_vector_type(4)));

#define EQ_SCALE   0.04419417382415922f     /* 1/sqrt(512) */
#define CONV_SCALE 0.014731391274719738f    /* 1/sqrt(512*9) */

// workspace layout (bytes)
#define WS_S   0                                  // f32 [8][512]
#define WS_ESC (16*1024)                          // f32 [8][512]  = conv_scale*demod
#define WS_WSQ (32*1024)                          // f32 [512][512]
#define WS_WT  (32*1024 + 1024*1024)              // bf16 [9][512][512]  (khw, o, ci)
#define WS_XS  (WS_WT + 9*512*512*2)              // bf16 [8][64][64][512] (b, y, x, ci)
#define WS_Z   (WS_XS + 8*64*64*512*2)            // bf16 zero page, 64 KB

__device__ __forceinline__ void gld16(void* l, const void* g) {
  __builtin_amdgcn_global_load_lds((const __attribute__((address_space(1))) void*)g,
                                   (__attribute__((address_space(3))) void*)l,
                                   16, 0, 0);
}

// round-to-nearest-even f32 -> bf16 bits
__device__ __forceinline__ u16 f2b_rne(float f) {
  union { float f; unsigned int i; } c; c.f = f;
  unsigned int r = (c.i + 0x7FFFu + ((c.i >> 16) & 1u)) >> 16;
  return (u16)r;
}

// one wave per output: s[b][i] = eq_scale * dot(style[b], modw[i]) + mod_bias[i]
__global__ void k_style(const float* __restrict__ style, const float* __restrict__ mw,
                        const float* __restrict__ mb, float* __restrict__ s) {
  int g = blockIdx.x * 4 + (threadIdx.x >> 6);   // 1024 blocks x 4 waves = 4096
  int lane = threadIdx.x & 63;
  int b = g >> 9, i = g & 511;
  const float4* sr = (const float4*)(style + (b << 9));
  const float4* wr = (const float4*)(mw + (i << 9));
  float acc = 0.f;
#pragma unroll
  for (int j = 0; j < 2; ++j) {
    float4 a = sr[lane * 2 + j];
    float4 w4 = wr[lane * 2 + j];
    acc += a.x * w4.x + a.y * w4.y + a.z * w4.z + a.w * w4.w;
  }
#pragma unroll
  for (int off = 32; off; off >>= 1) acc += __shfl_xor(acc, off);
  if (lane == 0) s[g] = acc * EQ_SCALE + mb[i];
}

// wsq[o][i] = sum_khw weight[o][i][khw]^2
__global__ void k_wsq(const float* __restrict__ w, float* __restrict__ wsq) {
  int idx = blockIdx.x * 256 + threadIdx.x;      // 262144
  const float* p = w + idx * 9;
  float a = 0.f;
  for (int t = 0; t < 9; ++t) { float v = p[t]; a += v * v; }
  wsq[idx] = a;
}

// one wave per output: esc[b][o] = conv_scale * rsqrt(conv_scale^2 * dot(wsq[o], s[b]^2) + 1e-8)
__global__ void k_esc(const float* __restrict__ wsq, const float* __restrict__ s,
                      float* __restrict__ esc) {
  int g = blockIdx.x * 4 + (threadIdx.x >> 6);   // 1024 blocks x 4 waves = 4096
  int lane = threadIdx.x & 63;
  int b = g >> 9, o = g & 511;
  const float4* wr = (const float4*)(wsq + (o << 9));
  const float4* sr = (const float4*)(s + (b << 9));
  float a = 0.f;
#pragma unroll
  for (int j = 0; j < 2; ++j) {
    float4 wv = wr[lane * 2 + j];
    float4 sv = sr[lane * 2 + j];
    a += wv.x * sv.x * sv.x + wv.y * sv.y * sv.y + wv.z * sv.z * sv.z + wv.w * sv.w * sv.w;
  }
#pragma unroll
  for (int off = 32; off; off >>= 1) a += __shfl_xor(a, off);
  if (lane == 0) esc[g] = CONV_SCALE * rsqrtf(CONV_SCALE * CONV_SCALE * a + 1e-8f);
}

// zero page for OOB-row staging redirect
__global__ void k_zero(u64* __restrict__ z) {
  z[blockIdx.x * 256 + threadIdx.x] = 0ull;      // 32*256*8 = 64 KB
}

// Wt[khw][o][i] = bf16(weight[o][i][khw])   (f32 -> bf16 relayout)
__global__ void k_wt(const float* __restrict__ w, u16* __restrict__ wt) {
  int idx = blockIdx.x * 256 + threadIdx.x;      // 262144 = o*512 + i
  const float* p = w + idx * 9;
  for (int t = 0; t < 9; ++t) wt[t * 262144 + idx] = f2b_rne(p[t]);
}

// xs[b][y][x][i] = bf16( x[b][i][y][x] * s[b][i] )   (NCHW->NHWC transpose + scale)
__global__ void k_xs(const float* __restrict__ x, const float* __restrict__ s,
                     u16* __restrict__ xs) {
  __shared__ u16 tile[64 * 66];
  int by = blockIdx.x;                 // b*64 + y
  int i0 = blockIdx.y << 6;
  int b = by >> 6, y = by & 63;
  int t = threadIdx.x, w = t >> 6, lane = t & 63;
  for (int k = 0; k < 16; ++k) {
    int il = w + (k << 2);
    int i = i0 + il;
    float v = x[((((b << 9) + i) << 6) | y) << 6 | lane] * s[(b << 9) + i];
    tile[lane * 66 + il] = f2b_rne(v);
  }
  __syncthreads();
  for (int k = 0; k < 16; ++k) {
    int xc = w + (k << 2);
    xs[((((b << 6) | y) << 6 | xc) << 9) + i0 + lane] = tile[xc * 66 + lane];
  }
}

// Conv: implicit GEMM. Block tile 128(o) x 256(4 rows x 64 cols), 8 waves (2og x 4row),
// wave 64x64, A+B both in LDS. Counted-vmcnt pipeline: ONE raw s_barrier per tap,
// staging loads stay in flight across it (never a full drain in the main loop).
__global__ void __launch_bounds__(512, 1) k_conv(
    const u16* __restrict__ wt, const u16* __restrict__ xs,
    const u16* __restrict__ zbuf,
    const float* __restrict__ esc, const float* __restrict__ noise,
    const float* __restrict__ nwp, const float* __restrict__ abias,
    float* __restrict__ out) {
  __shared__ __align__(16) u16 ldsA[2][128 * 64];   // 2 x 16 KB, xor-swizzled chunks
  __shared__ __align__(16) u16 ldsB[2][384 * 64];   // 2 x 48 KB: 6 input rows x 64 cols

  const int t = threadIdx.x;
  const int w = t >> 6, lane = t & 63;
  const int wm = w >> 2, wrw = w & 3;           // 2(o-group) x 4(row) wave grid
  const int quad = lane >> 4, l15 = lane & 15;

  // XCD swizzle: each XCD owns one 128-o slice of wt (1.1 MB/cib-pass, L2-resident).
  const int flat = blockIdx.y * 4 + blockIdx.x;   // 0..511
  const int xcd = flat & 7, rest = flat >> 3;     // 8 x 64
  const int o0 = (xcd & 3) << 7;
  const int nt = (rest << 1) | (xcd >> 2);        // 0..127, bijective
  const int b = nt >> 4, y0 = (nt & 15) << 2;     // 4 output rows per tile

  // B staging source pointers; chunk j covers LDS row tr==j (input row y0-1+j).
  // OOB rows redirect to the zero page -> no row masking anywhere in compute.
  const u16* bgp[6];
#pragma unroll
  for (int j = 0; j < 6; ++j) {
    int c = j * 512 + t;
    int pos = c >> 3, swz = c & 7;
    int ci16 = swz ^ (pos & 7);
    int col = pos & 63;
    int yy = y0 - 1 + j;
    if ((unsigned)yy < 64u)
      bgp[j] = xs + ((((b << 6) + yy) << 6) + col) * 512 + ci16 * 8;
    else
      bgp[j] = zbuf + col * 512 + ci16 * 8;
  }
  // A staging gather offsets (element units, add khw/cib at issue)
  int agOff[2];
#pragma unroll
  for (int j = 0; j < 2; ++j) {
    int c = j * 512 + t;
    int ol = c >> 3, swz = c & 7;
    int ci16 = swz ^ (ol & 7);
    agOff[j] = (o0 + ol) * 512 + ci16 * 8;
  }

  f32x4 acc[16];
#pragma unroll
  for (int i = 0; i < 16; ++i) acc[i] = (f32x4)0.f;

  int aBase[4], aXor[4];
#pragma unroll
  for (int mf = 0; mf < 4; ++mf) {
    int ol = wm * 64 + mf * 16 + l15;
    aBase[mf] = ol * 8;
    aXor[mf] = ol & 7;
  }

  // prologue: stage B[cib0] and A[tap 0,0]; first tap's vmcnt(0)+barrier makes visible
#pragma unroll
  for (int j = 0; j < 6; ++j)
    gld16(&ldsB[0][(j * 512 + w * 64) * 8], bgp[j]);
#pragma unroll
  for (int j = 0; j < 2; ++j)
    gld16(&ldsA[0][(j * 512 + w * 64) * 8], wt + agOff[j]);

#pragma unroll 1
  for (int cib = 0; cib < 8; ++cib) {
    const u16* bR = &ldsB[cib & 1][0];
#pragma unroll
    for (int khw = 0; khw < 9; ++khw) {
      // counted wait: my stage for THIS tap's A buffer must have landed (it was
      // issued one full tap ago). At khw==7 the 6 B-prefetch loads (issued khw==6)
      // are allowed to remain in flight; they drain at khw==8's vmcnt(0).
      if (khw == 7) { asm volatile("s_waitcnt vmcnt(6)" ::: "memory"); }
      else         { asm volatile("s_waitcnt vmcnt(0)" ::: "memory"); }
      __builtin_amdgcn_s_barrier();
      __builtin_amdgcn_sched_barrier(0);

      const int par = (cib + khw) & 1;
      const u16* aR = &ldsA[par][0];

      // issue next tap's A stage into the other parity buffer (wraps harmlessly
      // at the very end; drained by the post-loop vmcnt(0))
      {
        u16* aW = (u16*)&ldsA[par ^ 1][0];
        const int nkhw = (khw == 8) ? 0 : khw + 1;
        const int ncib = (khw == 8) ? ((cib + 1) & 7) : cib;
#pragma unroll
        for (int j = 0; j < 2; ++j)
          gld16(aW + (j * 512 + w * 64) * 8,
                wt + agOff[j] + nkhw * 262144 + ncib * 64);
      }
      // issue next cib's B tile (always, so vmcnt counts stay compile-time;
      // at cib==7 this re-stages cib 0 into the dead buffer: harmless)
      if (khw == 6) {
        u16* bW = (u16*)&ldsB[(cib & 1) ^ 1][0];
        const int pc = (cib + 1) & 7;
#pragma unroll
        for (int j = 0; j < 6; ++j)
          gld16(bW + (j * 512 + w * 64) * 8, bgp[j] + pc * 64);
      }

      const int kh = khw / 3, kw = khw % 3;
      const int tr = wrw + kh;                 // 0..5, always in-range (zero page)
      int bBase[4], bXor[4];
      unsigned cmask[4];
#pragma unroll
      for (int nf = 0; nf < 4; ++nf) {
        int ci = nf * 16 + l15 + kw - 1;
        cmask[nf] = ((kw == 0 && nf == 0) || (kw == 2 && nf == 3))
                        ? (unsigned)((unsigned)ci > 63u) : 0u;
        ci &= 63;
        int pos = tr * 64 + ci;
        bBase[nf] = pos * 8;
        bXor[nf] = pos & 7;
      }
#pragma unroll
      for (int ks = 0; ks < 2; ++ks) {
        const int kci = ks * 4 + quad;
        bf16x8 af[4], bv[4];
#pragma unroll
        for (int mf = 0; mf < 4; ++mf)
          af[mf] = *(const bf16x8*)(aR + (aBase[mf] + (kci ^ aXor[mf])) * 8);
#pragma unroll
        for (int nf = 0; nf < 4; ++nf) {
          bf16x8 v = *(const bf16x8*)(bR + (bBase[nf] + (kci ^ bXor[nf])) * 8);
          bf16x8 z = {0, 0, 0, 0, 0, 0, 0, 0};
          bv[nf] = cmask[nf] ? z : v;
        }
        __builtin_amdgcn_s_setprio(1);
#pragma unroll
        for (int mf = 0; mf < 4; ++mf)
#pragma unroll
          for (int nf = 0; nf < 4; ++nf)
            acc[mf * 4 + nf] = __builtin_amdgcn_mfma_f32_16x16x32_bf16(
                af[mf], bv[nf], acc[mf * 4 + nf], 0, 0, 0);
        __builtin_amdgcn_s_setprio(0);
      }
    }
  }
  // drain the wrapped tail stage before LDS goes away
  asm volatile("s_waitcnt vmcnt(0)" ::: "memory");

  // epilogue: scale + noise + bias + leaky_relu*sqrt(2), f32 store
  const float nwv = nwp[0];
  const int y = y0 + wrw;
#pragma unroll
  for (int mf = 0; mf < 4; ++mf) {
#pragma unroll
    for (int r = 0; r < 4; ++r) {
      int o = o0 + wm * 64 + mf * 16 + quad * 4 + r;
      float es = esc[(b << 9) + o];
      float ab = abias[o];
      int rowbase = ((((b << 9) + o) << 6) | y) << 6;
#pragma unroll
      for (int nf = 0; nf < 4; ++nf) {
        int col = nf * 16 + l15;
        int idx = rowbase | col;
        float v = acc[mf * 4 + nf][r] * es + nwv * noise[idx] + ab;
        v = (v < 0.f ? 0.2f * v : v) * 1.4142135623730951f;
        out[idx] = v;
      }
    }
  }
}

extern "C" void kernel_launch(void* const* d_in, const int* in_sizes, int n_in,
                              void* d_out, int out_size, void* d_ws, size_t ws_size,
                              hipStream_t stream) {
  const float* x      = (const float*)d_in[0];
  const float* style  = (const float*)d_in[1];
  const float* noise  = (const float*)d_in[2];
  const float* weight = (const float*)d_in[3];
  const float* mw     = (const float*)d_in[4];
  const float* mb     = (const float*)d_in[5];
  const float* nw     = (const float*)d_in[6];
  const float* ab     = (const float*)d_in[7];
  float* out = (float*)d_out;

  char* ws = (char*)d_ws;
  float* s   = (float*)(ws + WS_S);
  float* esc = (float*)(ws + WS_ESC);
  float* wsq = (float*)(ws + WS_WSQ);
  u16* wt    = (u16*)(ws + WS_WT);
  u16* xs    = (u16*)(ws + WS_XS);
  u16* zbuf  = (u16*)(ws + WS_Z);

  k_zero<<<32, 256, 0, stream>>>((u64*)zbuf);
  k_style<<<1024, 256, 0, stream>>>(style, mw, mb, s);
  k_wsq<<<1024, 256, 0, stream>>>(weight, wsq);
  k_esc<<<1024, 256, 0, stream>>>(wsq, s, esc);
  k_wt<<<1024, 256, 0, stream>>>(weight, wt);
  k_xs<<<dim3(512, 8), 256, 0, stream>>>(x, s, xs);
  k_conv<<<dim3(4, 128), 512, 0, stream>>>(wt, xs, zbuf, esc, noise, nw, ab, out);
}

// Round 4
// 353.094 us; speedup vs baseline: 1.3837x; 1.0337x over previous
//
#include <hip/hip_runtime.h>
#include <hip/hip_bf16.h>

typedef unsigned short u16;
typedef unsigned long long u64;
typedef short bf16x8 __attribute__((ext_vector_type(8)));
typedef float f32x4 __attribute__((ext_vector_type(4)));

#define EQ_SCALE   0.04419417382415922f     /* 1/sqrt(512) */
#define CONV_SCALE 0.014731391274719738f    /* 1/sqrt(512*9) */

// workspace layout (bytes)
#define WS_S   0                                  // f32 [8][512]
#define WS_ESC (16*1024)                          // f32 [8][512]  = conv_scale*demod
#define WS_WSQ (32*1024)                          // f32 [512][512]
#define WS_WT  (32*1024 + 1024*1024)              // bf16 [9][512][512]  (khw, o, ci)
#define WS_XS  (WS_WT + 9*512*512*2)              // bf16 [8][64][64][512] (b, y, x, ci)
#define WS_Z   (WS_XS + 8*64*64*512*2)            // bf16 zero page, 64 KB

__device__ __forceinline__ void gld16(void* l, const void* g) {
  __builtin_amdgcn_global_load_lds((const __attribute__((address_space(1))) void*)g,
                                   (__attribute__((address_space(3))) void*)l,
                                   16, 0, 0);
}

// round-to-nearest-even f32 -> bf16 bits
__device__ __forceinline__ u16 f2b_rne(float f) {
  union { float f; unsigned int i; } c; c.f = f;
  unsigned int r = (c.i + 0x7FFFu + ((c.i >> 16) & 1u)) >> 16;
  return (u16)r;
}

// fused prep 1: zero page (32 blocks) + wsq (1024 blocks) + style (1024 blocks)
__global__ void __launch_bounds__(256) k_pre1(
    const float* __restrict__ style, const float* __restrict__ mw,
    const float* __restrict__ mb, const float* __restrict__ w,
    float* __restrict__ s, float* __restrict__ wsq, u64* __restrict__ z) {
  int bid = blockIdx.x, t = threadIdx.x;
  if (bid < 32) { z[bid * 256 + t] = 0ull; return; }
  if (bid < 1056) {                              // wsq[o][i] = sum_khw w[o][i][khw]^2
    int idx = (bid - 32) * 256 + t;
    const float* p = w + idx * 9;
    float a = 0.f;
#pragma unroll
    for (int k = 0; k < 9; ++k) { float v = p[k]; a += v * v; }
    wsq[idx] = a;
    return;
  }
  // style: one wave per output, s[b][i] = eq_scale*dot(style[b], mw[i]) + mb[i]
  int g = (bid - 1056) * 4 + (t >> 6);           // 4096
  int lane = t & 63;
  int b = g >> 9, i = g & 511;
  const float4* sr = (const float4*)(style + (b << 9));
  const float4* wr = (const float4*)(mw + (i << 9));
  float acc = 0.f;
#pragma unroll
  for (int j = 0; j < 2; ++j) {
    float4 a4 = sr[lane * 2 + j];
    float4 w4 = wr[lane * 2 + j];
    acc += a4.x * w4.x + a4.y * w4.y + a4.z * w4.z + a4.w * w4.w;
  }
#pragma unroll
  for (int off = 32; off; off >>= 1) acc += __shfl_xor(acc, off);
  if (lane == 0) s[g] = acc * EQ_SCALE + mb[i];
}

// fused prep 2: esc (1024) + wt relayout (1024) + xs transpose/scale (4096)
__global__ void __launch_bounds__(256) k_pre2(
    const float* __restrict__ wsq, const float* __restrict__ s,
    const float* __restrict__ w, const float* __restrict__ x,
    float* __restrict__ esc, u16* __restrict__ wt, u16* __restrict__ xs) {
  __shared__ u16 tile[64 * 66];
  int bid = blockIdx.x, t = threadIdx.x;
  if (bid < 1024) {                              // esc, one wave per output
    int g = bid * 4 + (t >> 6);
    int lane = t & 63;
    int b = g >> 9, o = g & 511;
    const float4* wr = (const float4*)(wsq + (o << 9));
    const float4* sr = (const float4*)(s + (b << 9));
    float a = 0.f;
#pragma unroll
    for (int j = 0; j < 2; ++j) {
      float4 wv = wr[lane * 2 + j];
      float4 sv = sr[lane * 2 + j];
      a += wv.x*sv.x*sv.x + wv.y*sv.y*sv.y + wv.z*sv.z*sv.z + wv.w*sv.w*sv.w;
    }
#pragma unroll
    for (int off = 32; off; off >>= 1) a += __shfl_xor(a, off);
    if (lane == 0) esc[g] = CONV_SCALE * rsqrtf(CONV_SCALE * CONV_SCALE * a + 1e-8f);
    return;
  }
  if (bid < 2048) {                              // wt[khw][o][i] = bf16(w[o][i][khw])
    int idx = (bid - 1024) * 256 + t;
    const float* p = w + idx * 9;
#pragma unroll
    for (int k = 0; k < 9; ++k) wt[k * 262144 + idx] = f2b_rne(p[k]);
    return;
  }
  // xs[b][y][x][i] = bf16(x[b][i][y][x] * s[b][i])
  int v = bid - 2048;                            // 0..4095
  int by = v & 511, i0 = (v >> 9) << 6;
  int b = by >> 6, y = by & 63;
  int wv = t >> 6, lane = t & 63;
  for (int k = 0; k < 16; ++k) {
    int il = wv + (k << 2);
    int i = i0 + il;
    float val = x[((((b << 9) + i) << 6) | y) << 6 | lane] * s[(b << 9) + i];
    tile[lane * 66 + il] = f2b_rne(val);
  }
  __syncthreads();
  for (int k = 0; k < 16; ++k) {
    int xc = wv + (k << 2);
    xs[((((b << 6) | y) << 6 | xc) << 9) + i0 + lane] = tile[xc * 66 + lane];
  }
}

// Conv: implicit GEMM. Block tile 256(o) x 256(4 rows x 64 cols), 8 waves (2og x 4row),
// wave tile 128(o) x 64(pos) -> 42.7 FLOP per LDS byte (matrix pipe finally the
// longest pipe). A+B in LDS, 160 KB total, 1 block/CU, grid = 256 = one round.
// Counted-vmcnt pipeline, one s_barrier per tap.
__global__ void __launch_bounds__(512, 1) k_conv(
    const u16* __restrict__ wt, const u16* __restrict__ xs,
    const u16* __restrict__ zbuf,
    const float* __restrict__ esc, const float* __restrict__ noise,
    const float* __restrict__ nwp, const float* __restrict__ abias,
    float* __restrict__ out) {
  __shared__ __align__(16) u16 ldsA[2][256 * 64];   // 2 x 32 KB, xor-swizzled chunks
  __shared__ __align__(16) u16 ldsB[2][384 * 64];   // 2 x 48 KB: 6 input rows x 64 cols

  const int t = threadIdx.x;
  const int w = t >> 6, lane = t & 63;
  const int wm = w >> 2, wrw = w & 3;           // 2(o-group of 128) x 4(row) wave grid
  const int quad = lane >> 4, l15 = lane & 15;

  // XCD pinning: xcds 0-3 own o-half 0, xcds 4-7 own o-half 1 (2.25 MB/half, L2-fit).
  const int flat = blockIdx.y * 2 + blockIdx.x;   // 0..255
  const int xcd = flat & 7, rest = flat >> 3;     // 8 x 32
  const int o0 = (xcd >> 2) << 8;                 // 0 or 256
  const int nt = (rest << 2) | (xcd & 3);         // 0..127, bijective
  const int b = nt >> 4, y0 = (nt & 15) << 2;     // 4 output rows per tile

  // B staging source pointers; chunk j covers LDS row tr==j (input row y0-1+j).
  // OOB rows redirect to the zero page -> no row masking anywhere in compute.
  const u16* bgp[6];
#pragma unroll
  for (int j = 0; j < 6; ++j) {
    int c = j * 512 + t;
    int pos = c >> 3, swz = c & 7;
    int ci16 = swz ^ (pos & 7);
    int col = pos & 63;
    int yy = y0 - 1 + j;
    if ((unsigned)yy < 64u)
      bgp[j] = xs + ((((b << 6) + yy) << 6) + col) * 512 + ci16 * 8;
    else
      bgp[j] = zbuf + col * 512 + ci16 * 8;
  }
  // A staging gather offsets (element units; add khw/cib at issue). 4 chunks/thread.
  int agOff[4];
#pragma unroll
  for (int j = 0; j < 4; ++j) {
    int c = j * 512 + t;
    int ol = c >> 3, swz = c & 7;
    int ci16 = swz ^ (ol & 7);
    agOff[j] = (o0 + ol) * 512 + ci16 * 8;
  }

  f32x4 acc[32];
#pragma unroll
  for (int i = 0; i < 32; ++i) acc[i] = (f32x4)0.f;

  // A read addressing: ol = wm*128 + mf*16 + l15; xor = ol&7 = l15&7 (mf-independent)
  const int aBase0 = wm * 1024 + l15 * 8;       // chunk index base (x8 per ol)
  const int aXorS = l15 & 7;

  // prologue: stage B[cib0] (6) and A[tap 0,0] (4)
#pragma unroll
  for (int j = 0; j < 6; ++j)
    gld16(&ldsB[0][(j * 512 + w * 64) * 8], bgp[j]);
#pragma unroll
  for (int j = 0; j < 4; ++j)
    gld16(&ldsA[0][(j * 512 + w * 64) * 8], wt + agOff[j]);

#pragma unroll 1
  for (int cib = 0; cib < 8; ++cib) {
    const u16* bR = &ldsB[cib & 1][0];
#pragma unroll
    for (int khw = 0; khw < 9; ++khw) {
      // counted wait: this tap's A stage was issued one full tap ago. At khw==7
      // the 6 B-prefetch loads (issued khw==6) may stay in flight (vmcnt(6)).
      if (khw == 7) { asm volatile("s_waitcnt vmcnt(6)" ::: "memory"); }
      else         { asm volatile("s_waitcnt vmcnt(0)" ::: "memory"); }
      __builtin_amdgcn_s_barrier();
      __builtin_amdgcn_sched_barrier(0);

      const int par = (cib + khw) & 1;
      const u16* aR = &ldsA[par][0];

      // issue next tap's A stage into the other parity buffer (wraps harmlessly)
      {
        u16* aW = (u16*)&ldsA[par ^ 1][0];
        const int nkhw = (khw == 8) ? 0 : khw + 1;
        const int ncib = (khw == 8) ? ((cib + 1) & 7) : cib;
#pragma unroll
        for (int j = 0; j < 4; ++j)
          gld16(aW + (j * 512 + w * 64) * 8,
                wt + agOff[j] + nkhw * 262144 + ncib * 64);
      }
      // issue next cib's B tile (always at khw==6; compile-time vmcnt counts)
      if (khw == 6) {
        u16* bW = (u16*)&ldsB[(cib & 1) ^ 1][0];
        const int pc = (cib + 1) & 7;
#pragma unroll
        for (int j = 0; j < 6; ++j)
          gld16(bW + (j * 512 + w * 64) * 8, bgp[j] + pc * 64);
      }

      const int kh = khw / 3, kw = khw % 3;
      const int tr = wrw + kh;                 // 0..5, always in-range (zero page)
      int bBase[4], bXor[4];
      unsigned cmask[4];
#pragma unroll
      for (int nf = 0; nf < 4; ++nf) {
        int ci = nf * 16 + l15 + kw - 1;
        cmask[nf] = ((kw == 0 && nf == 0) || (kw == 2 && nf == 3))
                        ? (unsigned)((unsigned)ci > 63u) : 0u;
        ci &= 63;
        int pos = tr * 64 + ci;
        bBase[nf] = pos * 8;
        bXor[nf] = pos & 7;
      }
#pragma unroll
      for (int ks = 0; ks < 2; ++ks) {
        const int kci = ks * 4 + quad;
        bf16x8 af[8], bv[4];
#pragma unroll
        for (int mf = 0; mf < 8; ++mf)
          af[mf] = *(const bf16x8*)(aR + (aBase0 + mf * 128 + (kci ^ aXorS)) * 8);
#pragma unroll
        for (int nf = 0; nf < 4; ++nf) {
          bf16x8 v = *(const bf16x8*)(bR + (bBase[nf] + (kci ^ bXor[nf])) * 8);
          bf16x8 z = {0, 0, 0, 0, 0, 0, 0, 0};
          bv[nf] = cmask[nf] ? z : v;
        }
        __builtin_amdgcn_s_setprio(1);
#pragma unroll
        for (int mf = 0; mf < 8; ++mf)
#pragma unroll
          for (int nf = 0; nf < 4; ++nf)
            acc[mf * 4 + nf] = __builtin_amdgcn_mfma_f32_16x16x32_bf16(
                af[mf], bv[nf], acc[mf * 4 + nf], 0, 0, 0);
        __builtin_amdgcn_s_setprio(0);
      }
    }
  }
  // drain the wrapped tail stage before LDS goes away
  asm volatile("s_waitcnt vmcnt(0)" ::: "memory");

  // epilogue: scale + noise + bias + leaky_relu*sqrt(2), f32 store
  const float nwv = nwp[0];
  const int y = y0 + wrw;
#pragma unroll
  for (int mf = 0; mf < 8; ++mf) {
#pragma unroll
    for (int r = 0; r < 4; ++r) {
      int o = o0 + wm * 128 + mf * 16 + quad * 4 + r;
      float es = esc[(b << 9) + o];
      float ab = abias[o];
      int rowbase = ((((b << 9) + o) << 6) | y) << 6;
#pragma unroll
      for (int nf = 0; nf < 4; ++nf) {
        int col = nf * 16 + l15;
        int idx = rowbase | col;
        float v = acc[mf * 4 + nf][r] * es + nwv * noise[idx] + ab;
        v = (v < 0.f ? 0.2f * v : v) * 1.4142135623730951f;
        out[idx] = v;
      }
    }
  }
}

extern "C" void kernel_launch(void* const* d_in, const int* in_sizes, int n_in,
                              void* d_out, int out_size, void* d_ws, size_t ws_size,
                              hipStream_t stream) {
  const float* x      = (const float*)d_in[0];
  const float* style  = (const float*)d_in[1];
  const float* noise  = (const float*)d_in[2];
  const float* weight = (const float*)d_in[3];
  const float* mw     = (const float*)d_in[4];
  const float* mb     = (const float*)d_in[5];
  const float* nw     = (const float*)d_in[6];
  const float* ab     = (const float*)d_in[7];
  float* out = (float*)d_out;

  char* ws = (char*)d_ws;
  float* s   = (float*)(ws + WS_S);
  float* esc = (float*)(ws + WS_ESC);
  float* wsq = (float*)(ws + WS_WSQ);
  u16* wt    = (u16*)(ws + WS_WT);
  u16* xs    = (u16*)(ws + WS_XS);
  u16* zbuf  = (u16*)(ws + WS_Z);

  k_pre1<<<2080, 256, 0, stream>>>(style, mw, mb, weight, s, wsq, (u64*)zbuf);
  k_pre2<<<6144, 256, 0, stream>>>(wsq, s, weight, x, esc, wt, xs);
  k_conv<<<dim3(2, 128), 512, 0, stream>>>(wt, xs, zbuf, esc, noise, nw, ab, out);
}